// Round 18
// baseline (1910.285 us; speedup 1.0000x reference)
//
#include <hip/hip_runtime.h>

#define TT 512
#define II 64
#define HH 256
#define NG 16          // batch groups (16 rows each)
#define NS 8           // gate slices per group (32 channels each)
#define TAGM 0xFFFF0000FFFF0000ULL

typedef _Float16 half8 __attribute__((ext_vector_type(8)));
typedef float f32x4 __attribute__((ext_vector_type(4)));
typedef unsigned long long u64;

__device__ __forceinline__ float sigm(float x){ return 1.0f/(1.0f+__expf(-x)); }
__device__ __forceinline__ float tanhf_(float x){ float e=__expf(2.0f*x); return 1.0f-2.0f/(e+1.0f); }

union HU { _Float16 h; unsigned short u; };
__device__ __forceinline__ unsigned short h2u(float f){ HU x; x.h=(_Float16)f; return x.u; }

__device__ __forceinline__ half8 cvt8v(const float* __restrict__ p){
    f32x4 a = *(const f32x4*)p, b = *(const f32x4*)(p+4);
    half8 r;
    r[0]=(_Float16)a[0]; r[1]=(_Float16)a[1]; r[2]=(_Float16)a[2]; r[3]=(_Float16)a[3];
    r[4]=(_Float16)b[0]; r[5]=(_Float16)b[1]; r[6]=(_Float16)b[2]; r[7]=(_Float16)b[3];
    return r;
}

// Pin weight fragments into the AGPR file (opaque asm result cannot be
// rematerialized; AGPRs otherwise idle; MFMA reads A from AGPR directly).
__device__ __forceinline__ void pina(half8& v){ asm volatile("" : "+a"(v)); }
__device__ __forceinline__ void pinv(f32x4& v){ asm volatile("" : "+v"(v)); }

#define MFMA(A,B,C) __builtin_amdgcn_mfma_f32_16x16x32_f16((A),(B),(C),0,0,0)
#define ALOAD64(p)    __hip_atomic_load((p), __ATOMIC_RELAXED, __HIP_MEMORY_SCOPE_AGENT)
#define ASTORE64(p,v) __hip_atomic_store((p), (v), __ATOMIC_RELAXED, __HIP_MEMORY_SCOPE_AGENT)

// payload merge: u32 = {hi16 = payload of high tagged u32, lo16 = of low}
__device__ __forceinline__ unsigned pk(u64 v){
    return __builtin_amdgcn_perm((unsigned)(v>>32), (unsigned)v, 0x05040100u);
}

// Persistent gate-sliced, layer-pipelined 2-layer LSTM — TAGGED-DATA protocol
// (r8 semantics) fused with cooperative LDS staging (r15 traffic shape):
//  * producer: fire-and-forget tagged stores (u32 = {tag16|f16}); NO drain,
//    NO flag, NO post-store barrier. Tag = data-step+1 (h0: t+1, h1: t).
//  * consumer: speculative coalesced bulk-load of its 4 staging lines
//    (128 B/lane), per-word tag validation, s_sleep-backed retry. ~2 MALL
//    RTTs per superstep instead of r17's ~3.5 (drain+flag round-trips gone).
//  * mod-2 h slots; overwrite safety by <=1-step skew induction (each WG
//    consumes all-slices tagged data every step; r8 precedent, refchecked).
// 128 WGs x 256 thr: group=blockIdx%16, slice=blockIdx/16; wave owns 8 chans.
// Superstep t computes h0(t) [t<TT] and h1(t-1) [t>0].
__global__ __launch_bounds__(256,1) __attribute__((amdgpu_waves_per_eu(1)))
void lstm_pers(
    const float* __restrict__ x,
    const float* __restrict__ Wih0, const float* __restrict__ Whh0,
    const float* __restrict__ bih0, const float* __restrict__ bhh0,
    const float* __restrict__ Wih1, const float* __restrict__ Whh1,
    const float* __restrict__ bih1, const float* __restrict__ bhh1,
    const float* __restrict__ W1, const float* __restrict__ b1,
    const float* __restrict__ W2, const float* __restrict__ b2,
    u64* __restrict__ hb0t, u64* __restrict__ hb1t,
    float* __restrict__ out)
{
    // fragment-staging tile (payload, untagged): [16 lines][128 u64] = 16 KB
    __shared__ __align__(16) u64 fsh[16*128];
    // per-wave store-transpose tiles
    __shared__ __align__(16) unsigned short twv[4][2][16][8];   // 2 KB
    __shared__ __align__(16) float epi[16*256 + 16*128];        // 24 KB (epilogue)

    const int tid = threadIdx.x;
    const int w   = tid >> 6;
    const int l   = tid & 63;
    const int lr  = l & 15;
    const int lk  = l >> 4;
    const int g   = blockIdx.x & (NG-1);
    const int s   = blockIdx.x >> 4;
    const int gbase = g * 16;
    const int cw  = s*32 + w*8;
    const int wid = s*4 + w;          // wave id in group == chanblock (0..31)

    // ---- resident weight fragments (MFMA A-operand), pinned into AGPRs ----
    half8 wA0[10][2];   // layer0: kt<8 -> Whh0 (K=256), kt=8,9 -> Wih0 (K=64)
    half8 wA1[16][2];   // layer1: kt<8 -> Whh1, kt>=8 -> Wih1
    f32x4 bias0v[2], bias1v[2];
#pragma unroll
    for (int m=0;m<2;++m){
        const int n = (lr&3)*HH + cw + m*4 + (lr>>2);
#pragma unroll
        for (int kt=0;kt<10;++kt){
            const float* src = (kt<8) ? (Whh0 + (size_t)n*HH + kt*32 + lk*8)
                                      : (Wih0 + (size_t)n*II + (kt-8)*32 + lk*8);
            wA0[kt][m] = cvt8v(src);
            pina(wA0[kt][m]);
        }
#pragma unroll
        for (int kt=0;kt<16;++kt){
            const float* src = (kt<8) ? (Whh1 + (size_t)n*HH + kt*32 + lk*8)
                                      : (Wih1 + (size_t)n*HH + (kt-8)*32 + lk*8);
            wA1[kt][m] = cvt8v(src);
            pina(wA1[kt][m]);
        }
        const int cD = cw + m*4 + lk;
#pragma unroll
        for (int j=0;j<4;++j){
            bias0v[m][j] = bih0[j*HH+cD] + bhh0[j*HH+cD];
            bias1v[m][j] = bih1[j*HH+cD] + bhh1[j*HH+cD];
        }
        pinv(bias0v[m]); pinv(bias1v[m]);
    }

    float c0s0=0.f, c0s1=0.f, c1s0=0.f, c1s1=0.f;
    const int fo = lk*32 + lr*2;      // per-lane frag offset (payload u64)
    const int kt0 = 2*w;              // this wave's staged lines (pair w)

    // ---- x(0) register prefetch ----
    f32x4 xa, xb, xc, xd;
    {
        const float* xp = x + ((size_t)(gbase+lr)*TT)*II + lk*8;
        xa = *(const f32x4*)xp;      xb = *(const f32x4*)(xp+4);
        xc = *(const f32x4*)(xp+32); xd = *(const f32x4*)(xp+36);
    }

    half8 bh0[8] = {}, bh1[8] = {};   // current-step h fragments (B-operand)

    for (int t=0; t<=TT; ++t){
        f32x4 a0m0 = bias0v[0], a0m1 = bias0v[1];
        f32x4 a1m0 = bias1v[0], a1m1 = bias1v[1];

        // x-part of layer0 from prefetched registers
        if (t < TT){
            half8 bx0, bx1;
#pragma unroll
            for (int j=0;j<4;++j){
                bx0[j]   = (_Float16)xa[j];  bx0[4+j] = (_Float16)xb[j];
                bx1[j]   = (_Float16)xc[j];  bx1[4+j] = (_Float16)xd[j];
            }
            a0m0 = MFMA(wA0[8][0], bx0, a0m0);
            a0m1 = MFMA(wA0[8][1], bx0, a0m1);
            a0m0 = MFMA(wA0[9][0], bx1, a0m0);
            a0m1 = MFMA(wA0[9][1], bx1, a0m1);
        }

        if (t > 0){
            if (t < TT){
#pragma unroll
                for (int kt=0;kt<8;++kt){         // Whh0 * h0(t-1)
                    a0m0 = MFMA(wA0[kt][0], bh0[kt], a0m0);
                    a0m1 = MFMA(wA0[kt][1], bh0[kt], a0m1);
                }
            }
#pragma unroll
            for (int kt=0;kt<8;++kt){             // Wih1 * h0(t-1)
                a1m0 = MFMA(wA1[8+kt][0], bh0[kt], a1m0);
                a1m1 = MFMA(wA1[8+kt][1], bh0[kt], a1m1);
            }
            if (t >= 2){
#pragma unroll
                for (int kt=0;kt<8;++kt){         // Whh1 * h1(t-2)
                    a1m0 = MFMA(wA1[kt][0], bh1[kt], a1m0);
                    a1m1 = MFMA(wA1[kt][1], bh1[kt], a1m1);
                }
            }
        }

        // ---- activations -> wave-local LDS transpose tile ----
        if (t < TT){
            float ig=sigm(a0m0[0]), fg=sigm(a0m0[1]), gg=tanhf_(a0m0[2]), og=sigm(a0m0[3]);
            c0s0 = fg*c0s0 + ig*gg;
            twv[w][0][lr][lk]   = h2u(og*tanhf_(c0s0));
            float ig1=sigm(a0m1[0]), fg1=sigm(a0m1[1]), gg1=tanhf_(a0m1[2]), og1=sigm(a0m1[3]);
            c0s1 = fg1*c0s1 + ig1*gg1;
            twv[w][0][lr][lk+4] = h2u(og1*tanhf_(c0s1));
        }
        if (t > 0){
            float ig=sigm(a1m0[0]), fg=sigm(a1m0[1]), gg=tanhf_(a1m0[2]), og=sigm(a1m0[3]);
            c1s0 = fg*c1s0 + ig*gg;
            twv[w][1][lr][lk]   = h2u(og*tanhf_(c1s0));
            float ig1=sigm(a1m1[0]), fg1=sigm(a1m1[1]), gg1=tanhf_(a1m1[2]), og1=sigm(a1m1[3]);
            c1s1 = fg1*c1s1 + ig1*gg1;
            twv[w][1][lr][lk+4] = h2u(og1*tanhf_(c1s1));
        }
        asm volatile("s_waitcnt lgkmcnt(0)" ::: "memory");

        // ---- fire-and-forget TAGGED piece stores: lanes 0..31, 2 u64/layer,
        //      512B contiguous per wave; no drain, no flag ----
        if (l < 32){
            const int row = l >> 1, hf = l & 1;
            if (t < TT){
                u64 p = *(const u64*)&twv[w][0][row][hf*4];
                const unsigned tg = (unsigned)(t+1) << 16;
                u64 lo = (u64)(tg | (unsigned)(p & 0xFFFF))
                       | ((u64)(tg | (unsigned)((p>>16) & 0xFFFF)) << 32);
                u64 hi = (u64)(tg | (unsigned)((p>>32) & 0xFFFF))
                       | ((u64)(tg | (unsigned)((p>>48) & 0xFFFF)) << 32);
                u64* D = hb0t + ((size_t)((t&1)*NG + g))*2048 + wid*64 + l*2;
                ASTORE64(D,   lo);
                ASTORE64(D+1, hi);
            }
            if (t > 0){
                u64 p = *(const u64*)&twv[w][1][row][hf*4];
                const unsigned tg = (unsigned)t << 16;
                u64 lo = (u64)(tg | (unsigned)(p & 0xFFFF))
                       | ((u64)(tg | (unsigned)((p>>16) & 0xFFFF)) << 32);
                u64 hi = (u64)(tg | (unsigned)((p>>32) & 0xFFFF))
                       | ((u64)(tg | (unsigned)((p>>48) & 0xFFFF)) << 32);
                u64* D = hb1t + ((size_t)(((t-1)&1)*NG + g))*2048 + wid*64 + l*2;
                ASTORE64(D,   lo);
                ASTORE64(D+1, hi);
            }
        }

        if (t < TT){
            // x prefetch for t+1 (hides under the staging polls)
            if (t + 1 < TT){
                const float* xp = x + ((size_t)(gbase+lr)*TT + (t+1))*II + lk*8;
                xa = *(const f32x4*)xp;      xb = *(const f32x4*)(xp+4);
                xc = *(const f32x4*)(xp+32); xd = *(const f32x4*)(xp+36);
            }
            // ---- speculative cooperative staging with tag validation ----
            const u64 pat0 = ((u64)(t+1)<<16) | ((u64)(t+1)<<48);
            const u64 pat1 = ((u64)t<<16)     | ((u64)t<<48);
            const u64* T0 = hb0t + ((size_t)((t&1)*NG + g))*2048;
            const u64* T1 = hb1t + ((size_t)((t&1)*NG + g))*2048;  // slot (t-1)&1? see below
            // NOTE: h1 slot for data (t-1) is (t-1)&1; (t-1)&1 == (t&1)^1 for t>=1.
            const u64* T1s = hb1t + ((size_t)(((t >= 1 ? (t-1) : 0)&1)*NG + g))*2048;
            const bool need1 = (t >= 1);
            for (;;){
                bool ok = true;
#pragma unroll
                for (int j=0;j<2;++j){
                    const int kt = kt0 + j;
                    const u64* p = T0 + kt*256 + 2*fo;
                    u64 v0=ALOAD64(p), v1=ALOAD64(p+1), v2=ALOAD64(p+2), v3=ALOAD64(p+3);
                    ok = ok && ((v0&TAGM)==pat0) && ((v1&TAGM)==pat0)
                            && ((v2&TAGM)==pat0) && ((v3&TAGM)==pat0);
                    fsh[kt*128 + fo]     = (u64)pk(v0) | ((u64)pk(v1)<<32);
                    fsh[kt*128 + fo + 1] = (u64)pk(v2) | ((u64)pk(v3)<<32);
                }
                if (need1){
#pragma unroll
                    for (int j=0;j<2;++j){
                        const int kt = kt0 + j;
                        const u64* p = T1s + kt*256 + 2*fo;
                        u64 v0=ALOAD64(p), v1=ALOAD64(p+1), v2=ALOAD64(p+2), v3=ALOAD64(p+3);
                        ok = ok && ((v0&TAGM)==pat1) && ((v1&TAGM)==pat1)
                                && ((v2&TAGM)==pat1) && ((v3&TAGM)==pat1);
                        fsh[(8+kt)*128 + fo]     = (u64)pk(v0) | ((u64)pk(v1)<<32);
                        fsh[(8+kt)*128 + fo + 1] = (u64)pk(v2) | ((u64)pk(v3)<<32);
                    }
                }
                if (__all((int)ok)) break;
                __builtin_amdgcn_s_sleep(1);
            }
            (void)T1;
            __syncthreads();   // staging visible to all waves (drains LDS writes)
            // ---- read fragments from LDS into B-registers ----
#pragma unroll
            for (int kt=0;kt<8;++kt){
                union { u64 u[2]; half8 h; } cv;
                cv.u[0] = fsh[kt*128 + fo];
                cv.u[1] = fsh[kt*128 + fo + 1];
                bh0[kt] = cv.h;
            }
            if (need1){
#pragma unroll
                for (int kt=0;kt<8;++kt){
                    union { u64 u[2]; half8 h; } cv;
                    cv.u[0] = fsh[(8+kt)*128 + fo];
                    cv.u[1] = fsh[(8+kt)*128 + fo + 1];
                    bh1[kt] = cv.h;
                }
            }
            __syncthreads();   // all waves done reading fsh before next overwrite
        }
    }

    // ---- epilogue: slice 0 of each group computes the MLP head ----
    if (s == 0){
        float* hl  = epi;              // [16][256]
        float* zsh = epi + 16*256;     // [16][128]
        const u64 patE = ((u64)TT<<16) | ((u64)TT<<48);
        const u64* HL = hb1t + ((size_t)(((TT-1)&1)*NG + g))*2048;
        for (int i = tid; i < 1024; i += 256){
            const int r = i >> 6, q = i & 63;
            const size_t gi = (size_t)(q>>1)*32 + r*2 + (q&1);
            u64 a, b;
            do { a = ALOAD64(HL + gi*2);     } while ((a & TAGM) != patE);
            do { b = ALOAD64(HL + gi*2 + 1); } while ((b & TAGM) != patE);
            u64 v = (u64)pk(a) | ((u64)pk(b)<<32);
            union { u64 u; _Float16 h[4]; } cv; cv.u = v;
#pragma unroll
            for (int e=0;e<4;++e) hl[r*256 + q*4 + e] = (float)cv.h[e];
        }
        __syncthreads();
        for (int idx = tid; idx < 2048; idx += 256){
            const int r = idx >> 7, j = idx & 127;
            const float* wrow = W1 + j*HH;
            const float* hr = hl + r*256;
            float ssum = b1[j];
            for (int k=0;k<HH;k+=4){
                f32x4 wv = *(const f32x4*)(wrow + k);
                ssum += hr[k]*wv[0] + hr[k+1]*wv[1] + hr[k+2]*wv[2] + hr[k+3]*wv[3];
            }
            zsh[r*128 + j] = tanhf_(ssum);
        }
        __syncthreads();
        for (int idx = tid; idx < 1536; idx += 256){
            const int r = idx / 96, o = idx - r*96;
            const float* wrow = W2 + o*128;
            const float* zr = zsh + r*128;
            float ssum = b2[o];
            for (int k=0;k<128;k+=4){
                f32x4 wv = *(const f32x4*)(wrow + k);
                ssum += zr[k]*wv[0] + zr[k+1]*wv[1] + zr[k+2]*wv[2] + zr[k+3]*wv[3];
            }
            out[(size_t)(gbase+r)*96 + o] = ssum;
        }
    }
}

extern "C" void kernel_launch(void* const* d_in, const int* in_sizes, int n_in,
                              void* d_out, int out_size, void* d_ws, size_t ws_size,
                              hipStream_t stream) {
    const float* x    = (const float*)d_in[0];
    const float* Wih0 = (const float*)d_in[1];
    const float* Whh0 = (const float*)d_in[2];
    const float* bih0 = (const float*)d_in[3];
    const float* bhh0 = (const float*)d_in[4];
    const float* Wih1 = (const float*)d_in[5];
    const float* Whh1 = (const float*)d_in[6];
    const float* bih1 = (const float*)d_in[7];
    const float* bhh1 = (const float*)d_in[8];
    const float* W1   = (const float*)d_in[9];
    const float* b1   = (const float*)d_in[10];
    const float* W2   = (const float*)d_in[11];
    const float* b2   = (const float*)d_in[12];

    // workspace: tagged hb0 | hb1, each u64[2 slots][NG][2048] = 512 KB.
    // No flags, no memset: exact-tag matching makes poison/stale values inert.
    u64* hb0t = (u64*)d_ws;
    u64* hb1t = (u64*)((char*)d_ws + 524288);

    hipLaunchKernelGGL(lstm_pers, dim3(NG*NS), dim3(256), 0, stream,
                       x, Wih0, Whh0, bih0, bhh0,
                       Wih1, Whh1, bih1, bhh1,
                       W1, b1, W2, b2,
                       hb0t, hb1t, (float*)d_out);
}